// Round 11
// baseline (199.595 us; speedup 1.0000x reference)
//
#include <hip/hip_runtime.h>
#include <stdint.h>

typedef __attribute__((ext_vector_type(8))) short short8;
typedef __attribute__((ext_vector_type(4))) float floatx4;

__device__ inline unsigned short f2bf(float x) {
  union { float f; unsigned int u; } v; v.f = x;
  unsigned int r = v.u + 0x7FFFu + ((v.u >> 16) & 1u);  // RNE
  return (unsigned short)(r >> 16);
}

// ---------------------------------------------------------------------------
// pack_A: A_bf16[4096][2048] = bf16([x | h]). (R9, verified)
// ---------------------------------------------------------------------------
__global__ void pack_A(const float* __restrict__ x, const float* __restrict__ h,
                       unsigned short* __restrict__ A) {
  int gid = blockIdx.x * 256 + threadIdx.x;
  int row = gid >> 7;
  int kc  = (gid & 127) << 4;
  const float* src = (kc < 1024) ? (x + (size_t)row * 1024 + kc)
                                 : (h + (size_t)row * 1024 + (kc - 1024));
  const float4* s = (const float4*)src;
  float4 a = s[0], b = s[1], c = s[2], d = s[3];
  uint4 o0, o1;
  o0.x = f2bf(a.x) | ((unsigned)f2bf(a.y) << 16);
  o0.y = f2bf(a.z) | ((unsigned)f2bf(a.w) << 16);
  o0.z = f2bf(b.x) | ((unsigned)f2bf(b.y) << 16);
  o0.w = f2bf(b.z) | ((unsigned)f2bf(b.w) << 16);
  o1.x = f2bf(c.x) | ((unsigned)f2bf(c.y) << 16);
  o1.y = f2bf(c.z) | ((unsigned)f2bf(c.w) << 16);
  o1.z = f2bf(d.x) | ((unsigned)f2bf(d.y) << 16);
  o1.w = f2bf(d.z) | ((unsigned)f2bf(d.w) << 16);
  unsigned short* dst = A + (size_t)row * 2048 + kc;
  *(uint4*)dst = o0;
  *(uint4*)(dst + 8) = o1;
}

// ---------------------------------------------------------------------------
// pack_W: Wt_perm[4096][2048] = bf16(W^T), R = (h>>5)*128+((h>>4)&1)*64+
//         g*16+(h&15). (R9, verified)
// ---------------------------------------------------------------------------
__global__ void pack_W(const float* __restrict__ wi, const float* __restrict__ wh,
                       unsigned short* __restrict__ Wt) {
  __shared__ float tile[64][129];
  int b2 = blockIdx.x;
  int kt = b2 & 31;
  int nt = b2 >> 5;
  int k0 = kt << 6, n0 = nt << 7;
  const float* src = (k0 < 1024) ? (wi + (size_t)k0 * 4096)
                                 : (wh + (size_t)(k0 - 1024) * 4096);
  int t = threadIdx.x;
  int c4 = (t & 31) << 2, rr = t >> 5;
#pragma unroll
  for (int p = 0; p < 8; ++p) {
    int kk = rr + p * 8;
    float4 v = *(const float4*)(src + (size_t)kk * 4096 + n0 + c4);
    tile[kk][c4 + 0] = v.x; tile[kk][c4 + 1] = v.y;
    tile[kk][c4 + 2] = v.z; tile[kk][c4 + 3] = v.w;
  }
  __syncthreads();
  int k8 = (t & 7) << 3, nn = t >> 3;
#pragma unroll
  for (int p = 0; p < 4; ++p) {
    int nl = nn + p * 32;
    int n = n0 + nl;
    int hh = n & 1023, g = n >> 10;
    int R = ((hh >> 5) << 7) + (((hh >> 4) & 1) << 6) + (g << 4) + (hh & 15);
    uint4 o;
    o.x = f2bf(tile[k8 + 0][nl]) | ((unsigned)f2bf(tile[k8 + 1][nl]) << 16);
    o.y = f2bf(tile[k8 + 2][nl]) | ((unsigned)f2bf(tile[k8 + 3][nl]) << 16);
    o.z = f2bf(tile[k8 + 4][nl]) | ((unsigned)f2bf(tile[k8 + 5][nl]) << 16);
    o.w = f2bf(tile[k8 + 6][nl]) | ((unsigned)f2bf(tile[k8 + 7][nl]) << 16);
    *(uint4*)(Wt + (size_t)R * 2048 + k0 + k8) = o;
  }
}

// ---------------------------------------------------------------------------
// gemm_lstm R11: 256x256, 8 waves (2m x 4n), BK=64 — TWO barriers per tile,
// correct-depth counted vmcnt.
//   Convoy model (fits all 8 prior variants): symmetric barrier-locked waves
//   make LDS-read service and MFMA strictly alternate -> wall ~= LDS + MFMA
//   serial. Attack both terms: (a) 256^2/8-wave geometry minimizes chip LDS
//   reads (A amp 4x, B amp 2x -> 1500 cyc/tile/CU vs R7's 3000); (b) only
//   the 2 structurally-required barriers per tile (dbuf handoff + same-
//   parity B WAR), killing R1's 8-barrier lockstep skew (~1400 cyc/tile).
//   vmcnt(4) at tile end keeps B(t+2)'s 4 DMAs in flight, proves A(t+1) &
//   B(t+1) landed — never drains to 0 in-loop.
//   Per tile: [read k0 (B4+A8); stage A(t+1)->NA; lgkm0; MFMA k0 x32]
//             [read k1; lgkm0; BARRIER; stage B(t+2)->CB; MFMA k1 x32;
//              vmcnt(4); BARRIER]
// ---------------------------------------------------------------------------
__device__ inline void gl_lds16(const void* g, void* l) {
  __builtin_amdgcn_global_load_lds(
      (const __attribute__((address_space(1))) void*)g,
      (__attribute__((address_space(3))) void*)l, 16, 0, 0);
}

__device__ inline float sigm(float x)  { return 1.0f / (1.0f + __expf(-x)); }
__device__ inline float tanhx(float x) { return 2.0f / (1.0f + __expf(-2.0f * x)) - 1.0f; }

#define MFMA_BF16 __builtin_amdgcn_mfma_f32_16x16x32_bf16

// Stage a full 256-row x 64-k tile (32 KB) with 4 gl_lds per thread.
#define STAGE4(SRC, DSTARR)                                            \
  do {                                                                 \
    _Pragma("unroll")                                                  \
    for (int p = 0; p < 4; ++p)                                        \
      gl_lds16((SRC) + rOff + (size_t)p * 262144,                      \
               (char*)(DSTARR) + tid * 16 + p * 8192);                 \
  } while (0)

// One K-tile (see header).  CA/CB current A/B arrays, NA next-A array.
#define TILE(CA, CB, NA, AN, BN)                                              \
  {                                                                           \
    const char* aS = aBase + (size_t)(((AN) & 31) << 7);                      \
    const char* bS = bBase + (size_t)(((BN) & 31) << 7);                      \
    const char* pa_ = (const char*)(CA) + aRowOff;                            \
    const char* pb_ = (const char*)(CB) + bRowOff;                            \
    short8 a0[8], b0[4];                                                      \
    _Pragma("unroll")                                                         \
    for (int j = 0; j < 4; ++j) b0[j] = *(const short8*)(pb_ + j * 2048 + c0);\
    _Pragma("unroll")                                                         \
    for (int i = 0; i < 8; ++i) a0[i] = *(const short8*)(pa_ + i * 2048 + c0);\
    STAGE4(aS, NA);                                                           \
    asm volatile("s_waitcnt lgkmcnt(0)" ::: "memory");                        \
    __builtin_amdgcn_s_setprio(1);                                            \
    _Pragma("unroll")                                                         \
    for (int i = 0; i < 8; ++i)                                               \
      _Pragma("unroll")                                                       \
      for (int j = 0; j < 4; ++j)                                             \
        acc[i][j] = MFMA_BF16(a0[i], b0[j], acc[i][j], 0, 0, 0);              \
    __builtin_amdgcn_s_setprio(0);                                            \
    short8 a1[8], b1[4];                                                      \
    _Pragma("unroll")                                                         \
    for (int j = 0; j < 4; ++j) b1[j] = *(const short8*)(pb_ + j * 2048 + c1);\
    _Pragma("unroll")                                                         \
    for (int i = 0; i < 8; ++i) a1[i] = *(const short8*)(pa_ + i * 2048 + c1);\
    asm volatile("s_waitcnt lgkmcnt(0)" ::: "memory");                        \
    __builtin_amdgcn_s_barrier();                                             \
    STAGE4(bS, CB);                                                           \
    __builtin_amdgcn_s_setprio(1);                                            \
    _Pragma("unroll")                                                         \
    for (int i = 0; i < 8; ++i)                                               \
      _Pragma("unroll")                                                       \
      for (int j = 0; j < 4; ++j)                                             \
        acc[i][j] = MFMA_BF16(a1[i], b1[j], acc[i][j], 0, 0, 0);              \
    __builtin_amdgcn_s_setprio(0);                                            \
    asm volatile("s_waitcnt vmcnt(4)" ::: "memory");                          \
    __builtin_amdgcn_s_barrier();                                             \
  }

__global__ void __launch_bounds__(512, 2) gemm_lstm(
    const unsigned short* __restrict__ A,
    const unsigned short* __restrict__ Bt,
    const float* __restrict__ ct,
    const float* __restrict__ bi,
    const float* __restrict__ bh,
    float* __restrict__ out) {
  __shared__ __align__(16) char A0[32768];
  __shared__ __align__(16) char A1[32768];
  __shared__ __align__(16) char B0[32768];
  __shared__ __align__(16) char B1[32768];

  const int tid  = threadIdx.x;
  const int lane = tid & 63;
  const int wave = tid >> 6;
  const int wm = wave >> 2;        // 0..1  (M half: 128 rows)
  const int wn = wave & 3;         // 0..3  (N quarter: 64 rows)

  // ---- XCD swizzle (bijection on [0,256)) ----
  const int bid = blockIdx.x;
  const int gx = bid & 7;
  const int sx = bid >> 3;
  const int bx = (gx << 1) + (sx & 1);   // 0..15
  const int by = sx >> 1;                // 0..15
  const int m0 = by << 8;

  // ---- epilogue mapping + bias preload (R1-verified algebra) ----
  const int ec = lane & 15;
  const int h  = (bx << 6) + ((wn >> 1) << 5) + ((wn & 1) << 4) + ec;
  float bias[4];
#pragma unroll
  for (int j = 0; j < 4; ++j) bias[j] = bi[j * 1024 + h] + bh[j * 1024 + h];

  // ---- staging addressing (XOR-8 source swizzle, linear LDS) ----
  const int sr = tid >> 3;                                  // row 0..63
  const unsigned swz = (unsigned)(((tid & 7) ^ (sr & 7)) << 4);
  const size_t rOff = (size_t)sr * 4096 + swz;
  const char* aBase = (const char*)A  + (size_t)m0 * 4096;
  const char* bBase = (const char*)Bt + (size_t)(bx << 8) * 4096;

  // ---- LDS fragment addressing (swizzled read side) ----
  const int lr  = lane & 15;
  const int kq  = lane >> 4;
  const int key = lane & 7;
  const int c0  = (kq ^ key) << 4;
  const int c1  = ((4 + kq) ^ key) << 4;
  const int aRowOff = ((wm << 7) + lr) * 128;
  const int bRowOff = ((wn << 6) + lr) * 128;

  floatx4 acc[8][4] = {};

  // ---- prologue: B(0)->B0, A(0)->A0, B(1)->B1; vmcnt(4) keeps B(1) flying.
  STAGE4(bBase, B0);
  STAGE4(aBase, A0);
  STAGE4(bBase + 128, B1);
  asm volatile("s_waitcnt vmcnt(4)" ::: "memory");
  __builtin_amdgcn_s_barrier();

  for (int it = 0; it < 16; ++it) {
    const int t = it << 1;
    TILE(A0, B0, A1, t + 1, t + 2);   // even tile
    TILE(A1, B1, A0, t + 2, t + 3);   // odd tile
  }

  // ---- fused LSTM epilogue ----
  const int er = (lane >> 4) << 2;
  float cv[8][4];
#pragma unroll
  for (int i = 0; i < 8; ++i)
#pragma unroll
    for (int rg = 0; rg < 4; ++rg) {
      int row = m0 + (wm << 7) + i * 16 + er + rg;
      cv[i][rg] = ct[(size_t)row * 1024 + h];
    }
#pragma unroll
  for (int i = 0; i < 8; ++i) {
#pragma unroll
    for (int rg = 0; rg < 4; ++rg) {
      int row = m0 + (wm << 7) + i * 16 + er + rg;
      size_t o = (size_t)row * 1024 + h;
      float iv = sigm(acc[i][0][rg] + bias[0]);
      float fv = sigm(acc[i][1][rg] + bias[1]);
      float gv = tanhx(acc[i][2][rg] + bias[2]);
      float ov = sigm(acc[i][3][rg] + bias[3]);
      float cn = fv * cv[i][rg] + iv * gv;
      out[o] = ov * tanhx(cn);
      out[4194304 + o] = cn;
    }
  }
}

// ---------------------------------------------------------------------------
extern "C" void kernel_launch(void* const* d_in, const int* in_sizes, int n_in,
                              void* d_out, int out_size, void* d_ws, size_t ws_size,
                              hipStream_t stream) {
  const float* x  = (const float*)d_in[0];
  const float* ht = (const float*)d_in[1];
  const float* ct = (const float*)d_in[2];
  const float* wi = (const float*)d_in[3];
  const float* wh = (const float*)d_in[4];
  const float* bi = (const float*)d_in[5];
  const float* bh = (const float*)d_in[6];
  float* out = (float*)d_out;

  char* ws = (char*)d_ws;
  unsigned short* Abf = (unsigned short*)ws;                 // 16 MiB
  unsigned short* Wbf = (unsigned short*)(ws + (16u << 20)); // 16 MiB

  pack_A<<<2048, 256, 0, stream>>>(x, ht, Abf);
  pack_W<<<1024, 256, 0, stream>>>(wi, wh, Wbf);
  gemm_lstm<<<256, 512, 0, stream>>>(Abf, Wbf, ct, bi, bh, out);
}

// Round 12
// 194.877 us; speedup vs baseline: 1.0242x; 1.0242x over previous
//
#include <hip/hip_runtime.h>
#include <stdint.h>

typedef __attribute__((ext_vector_type(8))) short short8;
typedef __attribute__((ext_vector_type(4))) float floatx4;

__device__ inline unsigned short f2bf(float x) {
  union { float f; unsigned int u; } v; v.f = x;
  unsigned int r = v.u + 0x7FFFu + ((v.u >> 16) & 1u);  // RNE
  return (unsigned short)(r >> 16);
}

// ---------------------------------------------------------------------------
// pack_all: one dispatch does both packs. (verified; best-total config R7)
//   blocks [0,4096):    A_bf16[4096][2048] = bf16([x | h])
//   blocks [4096,6144): Wt_perm[4096][2048] = bf16(W^T) gate-interleaved:
//                       R = (h>>5)*128 + ((h>>4)&1)*64 + g*16 + (h&15)
// ---------------------------------------------------------------------------
__global__ void pack_all(const float* __restrict__ x, const float* __restrict__ h,
                         const float* __restrict__ wi, const float* __restrict__ wh,
                         unsigned short* __restrict__ A,
                         unsigned short* __restrict__ Wt) {
  int bid = blockIdx.x;
  int t = threadIdx.x;
  if (bid < 4096) {
    int idx = bid * 256 + t;
    int row = idx >> 8;
    int kc  = (idx & 255) << 3;
    const float* src = (kc < 1024) ? (x + (size_t)row * 1024 + kc)
                                   : (h + (size_t)row * 1024 + (kc - 1024));
    float4 a = ((const float4*)src)[0];
    float4 b = ((const float4*)src)[1];
    uint4 o;
    o.x = f2bf(a.x) | ((unsigned)f2bf(a.y) << 16);
    o.y = f2bf(a.z) | ((unsigned)f2bf(a.w) << 16);
    o.z = f2bf(b.x) | ((unsigned)f2bf(b.y) << 16);
    o.w = f2bf(b.z) | ((unsigned)f2bf(b.w) << 16);
    *(uint4*)(A + (size_t)row * 2048 + kc) = o;
  } else {
    __shared__ float tile[64][65];
    int b2 = bid - 4096;
    int kt = b2 & 31;
    int nt = b2 >> 5;
    int k0 = kt << 6, n0 = nt << 6;
    const float* src = (k0 < 1024) ? (wi + (size_t)k0 * 4096)
                                   : (wh + (size_t)(k0 - 1024) * 4096);
    int c4 = (t & 15) << 2, rr = t >> 4;
#pragma unroll
    for (int p = 0; p < 4; ++p) {
      int kk = rr + p * 16;
      float4 v = *(const float4*)(src + (size_t)kk * 4096 + n0 + c4);
      tile[kk][c4 + 0] = v.x; tile[kk][c4 + 1] = v.y;
      tile[kk][c4 + 2] = v.z; tile[kk][c4 + 3] = v.w;
    }
    __syncthreads();
    int k8 = (t & 7) << 3, nn = t >> 3;
#pragma unroll
    for (int p = 0; p < 2; ++p) {
      int n = n0 + nn + p * 32;          // global N index (gate*1024 + h)
      int hh = n & 1023, g = n >> 10;
      int R = ((hh >> 5) << 7) + (((hh >> 4) & 1) << 6) + (g << 4) + (hh & 15);
      int nl = nn + p * 32;
      uint4 o;
      o.x = f2bf(tile[k8 + 0][nl]) | ((unsigned)f2bf(tile[k8 + 1][nl]) << 16);
      o.y = f2bf(tile[k8 + 2][nl]) | ((unsigned)f2bf(tile[k8 + 3][nl]) << 16);
      o.z = f2bf(tile[k8 + 4][nl]) | ((unsigned)f2bf(tile[k8 + 5][nl]) << 16);
      o.w = f2bf(tile[k8 + 6][nl]) | ((unsigned)f2bf(tile[k8 + 7][nl]) << 16);
      *(uint4*)(Wt + (size_t)R * 2048 + k0 + k8) = o;
    }
  }
}

// ---------------------------------------------------------------------------
// gemm_lstm: R7 FINAL (best measured: 75.9 us gemm, 194.2 us total).
//   128x128 tile, BK=64, 4 waves, 2-barrier K-loop, global_load_lds w=16,
//   XOR-8 both-sides swizzle (0 conflicts), XCD supertile swizzle,
//   launch_bounds(256,4) -> 4 blocks/CU (1024 blocks = exactly 1 epoch),
//   fused LSTM epilogue (gate = j via pack permutation).
//   Session record (R0-R11): nine structural variants (8-phase, counted
//   vmcnt/lgkm, static bufs, sched-pin, 256^2/256x128 geometry, 1-4
//   blocks/CU) all land 76-85 us; this structure at 905 TF == documented
//   m97-family plain-HIP ceiling. NOT a HW roofline (MfmaUtil 39%) —
//   escaping requires the full co-designed m201/asm combo, which three
//   faithful reconstructions failed to reproduce here.
// ---------------------------------------------------------------------------
__device__ inline void gl_lds16(const void* g, void* l) {
  __builtin_amdgcn_global_load_lds(
      (const __attribute__((address_space(1))) void*)g,
      (__attribute__((address_space(3))) void*)l, 16, 0, 0);
}

__device__ inline float sigm(float x)  { return 1.0f / (1.0f + __expf(-x)); }
__device__ inline float tanhx(float x) { return 2.0f / (1.0f + __expf(-2.0f * x)) - 1.0f; }

__global__ void __launch_bounds__(256, 4) gemm_lstm(
    const unsigned short* __restrict__ A,
    const unsigned short* __restrict__ Bt,
    const float* __restrict__ ct,
    const float* __restrict__ bi,
    const float* __restrict__ bh,
    float* __restrict__ out) {
  constexpr int K = 2048;
  __shared__ char AsB[128 * 128];  // 128 rows x 64 bf16 (128 B)
  __shared__ char BsB[128 * 128];
  const int tid  = threadIdx.x;
  const int lane = tid & 63;
  const int wave = tid >> 6;
  const int wm = wave >> 1, wn = wave & 1;

  // ---- XCD supertile swizzle (bijection on [0,1024)) ----
  const int bid = blockIdx.x;
  const int g  = bid & 7;
  const int s  = bid >> 3;
  const int bx = (g << 2) + (s & 3);
  const int by = ((s >> 4) << 2) + ((s >> 2) & 3);
  const int m0 = by << 7;
  const int n0 = bx << 7;   // linear row block in permuted W
  const int h0 = bx << 5;   // 32 h per block

  // epilogue lane mapping + bias preload (latency hidden by K-loop)
  const int er = (lane >> 4) << 2;
  const int ec = lane & 15;
  const int h  = h0 + (wn << 4) + ec;
  float bias[4];
#pragma unroll
  for (int j = 0; j < 4; ++j) bias[j] = bi[j * 1024 + h] + bh[j * 1024 + h];

  // ---- staging: uniform base (SGPR) + ONE shared per-lane offset ----
  const int sr = tid >> 3;                              // LDS row 0..31 (+p*32)
  const int cs = ((tid & 7) ^ (sr & 7)) << 4;           // XOR-swizzled source chunk
  const unsigned voff = (unsigned)sr * 4096u + (unsigned)cs;  // per-lane, invariant
  const char* aBase = (const char*)A  + (size_t)m0 * 4096;    // row = 4096 B
  const char* bBase = (const char*)Bt + (size_t)n0 * 4096;
  char* aD = AsB + tid * 16;
  char* bD = BsB + tid * 16;

  floatx4 acc[4][4] = {};
  // LDS fragment bases (loop-invariant; f*16 rows -> +f*2048 immediate)
  const int rA = (wm << 6) + (lane & 15);
  const int rB = (wn << 6) + (lane & 15);
  const int keyc = lane & 7;
  const int kq   = lane >> 4;
  const char* aF0 = AsB + rA * 128 + ((kq ^ keyc) << 4);
  const char* aF1 = AsB + rA * 128 + (((4 + kq) ^ keyc) << 4);
  const char* bF0 = BsB + rB * 128 + ((kq ^ keyc) << 4);
  const char* bF1 = BsB + rB * 128 + (((4 + kq) ^ keyc) << 4);

  for (int ks = 0; ks < K; ks += 64) {
    const char* aIt = aBase + ks * 2;   // uniform
    const char* bIt = bBase + ks * 2;   // uniform
#pragma unroll
    for (int p = 0; p < 4; ++p) gl_lds16(aIt + p * 131072 + voff, aD + p * 4096);
#pragma unroll
    for (int p = 0; p < 4; ++p) gl_lds16(bIt + p * 131072 + voff, bD + p * 4096);
    __syncthreads();
    {
      short8 af[4], bfr[4];
#pragma unroll
      for (int f = 0; f < 4; ++f) {
        af[f]  = *(const short8*)(aF0 + f * 2048);
        bfr[f] = *(const short8*)(bF0 + f * 2048);
      }
#pragma unroll
      for (int i = 0; i < 4; ++i)
#pragma unroll
        for (int j = 0; j < 4; ++j)
          acc[i][j] = __builtin_amdgcn_mfma_f32_16x16x32_bf16(af[i], bfr[j], acc[i][j], 0, 0, 0);
    }
    {
      short8 af[4], bfr[4];
#pragma unroll
      for (int f = 0; f < 4; ++f) {
        af[f]  = *(const short8*)(aF1 + f * 2048);
        bfr[f] = *(const short8*)(bF1 + f * 2048);
      }
#pragma unroll
      for (int i = 0; i < 4; ++i)
#pragma unroll
        for (int j = 0; j < 4; ++j)
          acc[i][j] = __builtin_amdgcn_mfma_f32_16x16x32_bf16(af[i], bfr[j], acc[i][j], 0, 0, 0);
    }
    __syncthreads();
  }

  // ---- fused LSTM epilogue: batch ct loads, then lane-local gates ----
  float cv[4][4];
#pragma unroll
  for (int i = 0; i < 4; ++i)
#pragma unroll
    for (int rg = 0; rg < 4; ++rg) {
      int row = m0 + (wm << 6) + i * 16 + er + rg;
      cv[i][rg] = ct[(size_t)row * 1024 + h];
    }
#pragma unroll
  for (int i = 0; i < 4; ++i) {
#pragma unroll
    for (int rg = 0; rg < 4; ++rg) {
      int row = m0 + (wm << 6) + i * 16 + er + rg;
      size_t o = (size_t)row * 1024 + h;
      float iv = sigm(acc[i][0][rg] + bias[0]);
      float fv = sigm(acc[i][1][rg] + bias[1]);
      float gv = tanhx(acc[i][2][rg] + bias[2]);
      float ov = sigm(acc[i][3][rg] + bias[3]);
      float cn = fv * cv[i][rg] + iv * gv;
      out[o] = ov * tanhx(cn);
      out[4194304 + o] = cn;
    }
  }
}

// ---------------------------------------------------------------------------
extern "C" void kernel_launch(void* const* d_in, const int* in_sizes, int n_in,
                              void* d_out, int out_size, void* d_ws, size_t ws_size,
                              hipStream_t stream) {
  const float* x  = (const float*)d_in[0];
  const float* ht = (const float*)d_in[1];
  const float* ct = (const float*)d_in[2];
  const float* wi = (const float*)d_in[3];
  const float* wh = (const float*)d_in[4];
  const float* bi = (const float*)d_in[5];
  const float* bh = (const float*)d_in[6];
  float* out = (float*)d_out;

  char* ws = (char*)d_ws;
  unsigned short* Abf = (unsigned short*)ws;                 // 16 MiB
  unsigned short* Wbf = (unsigned short*)(ws + (16u << 20)); // 16 MiB

  pack_all<<<6144, 256, 0, stream>>>(x, ht, wi, wh, Abf, Wbf);
  gemm_lstm<<<1024, 256, 0, stream>>>(Abf, Wbf, ct, bi, bh, out);
}